// Round 15
// baseline (132.196 us; speedup 1.0000x reference)
//
#include <hip/hip_runtime.h>
#include <math.h>

constexpr int Bn  = 2;
constexpr int Cn  = 128;
constexpr int Hn  = 96;
constexpr int Wn  = 96;
constexpr int HWn = Hn * Wn;        // 9216
constexpr int CHWn = Cn * HWn;      // 1179648
constexpr int KCn = Cn * 9;         // 1152
constexpr float EPSn = 1e-5f;
constexpr int KPAD = 1160;          // LDS row stride in shorts (2320B)
constexpr int PXB  = 32;            // pixels per block

typedef short bf16x8 __attribute__((ext_vector_type(8)));
typedef float f32x4  __attribute__((ext_vector_type(4)));

static __device__ inline short f2bf(float f) {
    union { float f; unsigned u; } v; v.f = f;
    unsigned r = v.u + 0x7fff + ((v.u >> 16) & 1);
    return (short)(r >> 16);
}
// packed bf16 convert: lo = bf16(a), hi = bf16(b)
static __device__ inline unsigned pack2(float a, float b) {
    unsigned r;
    asm("v_cvt_pk_bf16_f32 %0, %1, %2" : "=v"(r) : "v"(a), "v"(b));
    return r;
}

// Fragment-shuffled dconv weights (round 13; each A-load = 1KB contiguous)
__global__ __launch_bounds__(256) void cvt_w_shuf(
    const float* __restrict__ w, short* __restrict__ wbs)
{
    int t = blockIdx.x * 256 + threadIdx.x;   // 147456
    if (t >= Cn * KCn) return;
    int e = t & 7, l = (t >> 3) & 63, rest = t >> 9;   // rest 0..287
    int j = rest % 36, wv = rest / 36;
    int lr = l & 15, lq = l >> 4;
    int o = wv * 16 + lr;
    int kidx = j * 32 + lq * 8 + e;
    int k = kidx >> 7, c = kidx & 127;
    wbs[t] = f2bf(w[o * KCn + c * 9 + k]);
}

// Fragment-shuffled offconv weights: index wvv encodes (mh=wvv&1, ks=wvv>>1)
__global__ __launch_bounds__(256) void cvt_ow_shuf(
    const float* __restrict__ ow, short* __restrict__ owbs)
{
    int t = blockIdx.x * 256 + threadIdx.x;   // 36864
    if (t >= 32 * KCn) return;
    int e = t & 7, l = (t >> 3) & 63, rest = t >> 9;   // rest 0..71
    int kk = rest % 9, wvv = rest / 9;
    int mh = wvv & 1, ks = wvv >> 1;
    int lr = l & 15, lq = l >> 4;
    int o = mh * 16 + lr;
    int kidx = ks * 288 + kk * 32 + lq * 8 + e;
    int k = kidx >> 7, c = kidx & 127;
    owbs[t] = (o < 27) ? f2bf(ow[o * KCn + c * 9 + k]) : (short)0;
}

// NCHW -> NHWC, dual output: f32 (residual-exact) + bf16 (gather path)
__global__ __launch_bounds__(256) void nchw2nhwc(
    const float* __restrict__ x, float* __restrict__ xTf,
    unsigned short* __restrict__ xTb)
{
    __shared__ float Tl[128][65];
    const int t = threadIdx.x;
    const int pix0 = blockIdx.x * 64;
    const int b   = pix0 / HWn;
    const int sp0 = pix0 - b * HWn;
    const float* xb = x + b * CHWn + sp0 + (t & 63);
    const int c0 = t >> 6;
#pragma unroll 8
    for (int i = 0; i < 32; ++i) {
        const int c = c0 + 4 * i;
        Tl[c][t & 63] = xb[c * HWn];
    }
    __syncthreads();
    float* dstf = xTf + pix0 * 128;
    unsigned short* dstb = xTb + pix0 * 128;
#pragma unroll 8
    for (int i = 0; i < 32; ++i) {
        const int o = t + 256 * i;
        float v = Tl[o & 127][o >> 7];
        dstf[o] = v;
        dstb[o] = (unsigned short)f2bf(v);
    }
}

// One fused residual block, 32 pixels / 512 threads, NHWC bf16 gathers,
// f32 residual, fragment-shuffled weights. Weight A-frags serve 2 px-columns.
__global__ __launch_bounds__(512, 4) void fused_stage(
    const unsigned short* __restrict__ xTb, const float* __restrict__ xTf,
    const short* __restrict__ wbs, const short* __restrict__ owbs,
    const float* __restrict__ obv,
    const float* __restrict__ gv, const float* __restrict__ bv,
    const float* __restrict__ mv, const float* __restrict__ vv,
    float* __restrict__ outTf, unsigned short* __restrict__ outTb,
    float* __restrict__ outC, int dil, int last)
{
    __shared__ short S[PXB * KPAD];           // 74240B im2col tile S[p][K']
    __shared__ float offL[PXB][18];
    __shared__ float maskL[PXB][9];

    const int t   = threadIdx.x;
    const int l   = t & 63;
    const int wv  = t >> 6;                   // wave 0..7
    const int lh  = l >> 5;                   // pixel half (gather-int)
    const int lc  = l & 31;                   // channel quad (gather-int)
    const int lr  = l & 15, lq = l >> 4;

    // XCD-aware bijective swizzle: 576 blocks = 8 XCDs x 72 contiguous
    const int bid = blockIdx.x;
    const int swz = (bid & 7) * 72 + (bid >> 3);
    const int pix0 = swz * PXB;               // 96%32==0: never crosses a row
    const int b   = pix0 / HWn;
    const int sp0 = pix0 - b * HWn;
    const int hy  = sp0 / Wn;
    const int wx0 = sp0 - hy * Wn;
    const int basep = b * HWn;

    // ---- gather-int: wave = 4 px; 18 iters (2 px-pairs x 9 taps), 6x3 ----
#pragma unroll
    for (int bch = 0; bch < 6; ++bch) {
        uint2 vle[3];
#pragma unroll
        for (int u = 0; u < 3; ++u) {
            const int it = bch * 3 + u;
            const int k  = it % 9;
            const int pi = it / 9;            // 0/1
            const int pp = wv * 4 + pi * 2 + lh;
            const int iy = hy + (k / 3 - 1) * dil;
            const int ix = wx0 + pp + (k % 3 - 1) * dil;
            const bool v = (iy >= 0) && (iy < Hn) && (ix >= 0) && (ix < Wn);
            const int aof = v ? (basep + iy * Wn + ix) : basep;
            uint2 val = ((const uint2*)(xTb + aof * 128))[lc];
            vle[u].x = v ? val.x : 0u;
            vle[u].y = v ? val.y : 0u;
        }
#pragma unroll
        for (int u = 0; u < 3; ++u) {
            const int it = bch * 3 + u;
            const int k  = it % 9;
            const int pi = it / 9;
            const int pp = wv * 4 + pi * 2 + lh;
            ((uint2*)&S[pp * KPAD + k * 128])[lc] = vle[u];
        }
    }
    __syncthreads();

    // ---- offconv GEMM: wave = (mh, ph, kh); K-half = 2 ks sections ----
    const int mh = wv & 1, ph = (wv >> 1) & 1, kh = wv >> 2;
    f32x4 oacc = {0.f, 0.f, 0.f, 0.f};
#pragma unroll
    for (int ks2 = 0; ks2 < 2; ++ks2) {
        const int ks = kh * 2 + ks2;
        const short* oarow = owbs + ((mh + ks * 2) * 9) * 512 + l * 8;
        const short* srow  = &S[(ph * 16 + lr) * KPAD + ks * 288 + lq * 8];
#pragma unroll
        for (int bch = 0; bch < 3; ++bch) {
            bf16x8 af[3], bf[3];
#pragma unroll
            for (int u = 0; u < 3; ++u) af[u] = *(const bf16x8*)(oarow + (bch * 3 + u) * 512);
#pragma unroll
            for (int u = 0; u < 3; ++u) bf[u] = *(const bf16x8*)(srow  + (bch * 3 + u) * 32);
#pragma unroll
            for (int u = 0; u < 3; ++u)
                oacc = __builtin_amdgcn_mfma_f32_16x16x32_bf16(af[u], bf[u], oacc, 0, 0, 0);
        }
    }
    __syncthreads();                           // S(int) reads done
    float* red = (float*)S;                    // 8 waves x 64 lanes x f32x4 = 8KB
    *(f32x4*)&red[wv * 256 + l * 4] = oacc;
    __syncthreads();
    if (wv < 4) {                              // wv encodes (mh, ph)
        f32x4 s0 = *(const f32x4*)&red[wv * 256 + l * 4];
        f32x4 s1 = *(const f32x4*)&red[(wv + 4) * 256 + l * 4];
        f32x4 sm = s0 + s1;
        const int px = (wv >> 1) * 16 + lr;
#pragma unroll
        for (int r = 0; r < 4; ++r) {
            int oc = (wv & 1) * 16 + lq * 4 + r;
            if (oc < 18) {
                offL[px][oc] = sm[r] + obv[oc];
            } else if (oc < 27) {
                float z = sm[r] + obv[oc];
                maskL[px][oc - 18] = 1.f / (1.f + expf(-z));
            }
        }
    }
    __syncthreads();                           // offL/maskL ready

    // ---- bilinear params: lane j (<36) computes set (pp=wv*4+j/9, k=j%9) ----
    int pw0i = 0, pw1i = 0, pw2i = 0, pw3i = 0, pa0 = 0, pa1 = 0, pdx = 0;
    if (l < 36) {
        const int p = wv * 4 + l / 9;
        const int k = l - 9 * (l / 9);
        const float offy = offL[p][2 * k];
        const float offx = offL[p][2 * k + 1];
        const float m    = maskL[p][k];
        const float py = (float)(hy + (k / 3 - 1) * dil) + offy;
        const float px = (float)(wx0 + p + (k % 3 - 1) * dil) + offx;
        const float y0f = floorf(py), x0f = floorf(px);
        const float ly = py - y0f, lx = px - x0f;
        const int y0 = (int)y0f, x0 = (int)x0f;
        const float yv0 = (y0 >= 0 && y0 < Hn)      ? 1.f : 0.f;
        const float yv1 = (y0 >= -1 && y0 < Hn - 1) ? 1.f : 0.f;
        const float xv0 = (x0 >= 0 && x0 < Wn)      ? 1.f : 0.f;
        const float xv1 = (x0 >= -1 && x0 < Wn - 1) ? 1.f : 0.f;
        const float wy0 = (1.f - ly) * yv0 * m;
        const float wy1 = ly * yv1 * m;
        const float wxa = (1.f - lx) * xv0;
        const float wxb = lx * xv1;
        pw0i = __float_as_int(wy0 * wxa);
        pw1i = __float_as_int(wy0 * wxb);
        pw2i = __float_as_int(wy1 * wxa);
        pw3i = __float_as_int(wy1 * wxb);
        const int y0c = min(max(y0, 0), Hn - 1), y1c = min(max(y0 + 1, 0), Hn - 1);
        const int x0c = min(max(x0, 0), Wn - 1), x1c = min(max(x0 + 1, 0), Wn - 1);
        pa0 = (basep + y0c * Wn + x0c) * 128;
        pa1 = (basep + y1c * Wn + x1c) * 128;
        pdx = (x1c - x0c) * 128;
    }

    // ---- gather-bil: 36 iters (4 px x 9 taps), 12 batches of 3 ----
#pragma unroll
    for (int bch = 0; bch < 12; ++bch) {
        unsigned u00[3], u01[3], u10[3], u11[3];
        float    w00[3], w01[3], w10[3], w11[3];
#pragma unroll
        for (int u = 0; u < 3; ++u) {
            const int i = bch * 3 + u;
            w00[u] = __int_as_float(__builtin_amdgcn_readlane(pw0i, i));
            w01[u] = __int_as_float(__builtin_amdgcn_readlane(pw1i, i));
            w10[u] = __int_as_float(__builtin_amdgcn_readlane(pw2i, i));
            w11[u] = __int_as_float(__builtin_amdgcn_readlane(pw3i, i));
            const int a00 = __builtin_amdgcn_readlane(pa0, i);
            const int a11 = __builtin_amdgcn_readlane(pa1, i);
            const int dxk = __builtin_amdgcn_readlane(pdx, i);
            const unsigned short* xp = xTb + a00;
            const unsigned short* xq = xTb + a11;
            u00[u] = ((const unsigned*)xp)[l];
            u01[u] = ((const unsigned*)(xp + dxk))[l];
            u10[u] = ((const unsigned*)(xq - dxk))[l];
            u11[u] = ((const unsigned*)xq)[l];
        }
#pragma unroll
        for (int u = 0; u < 3; ++u) {
            const int i  = bch * 3 + u;
            const int di = i / 9;              // 0..3
            const int k  = i - di * 9;
            const int pp = wv * 4 + di;
            const float f00a = __int_as_float(u00[u] << 16);
            const float f00b = __int_as_float(u00[u] & 0xffff0000u);
            const float f01a = __int_as_float(u01[u] << 16);
            const float f01b = __int_as_float(u01[u] & 0xffff0000u);
            const float f10a = __int_as_float(u10[u] << 16);
            const float f10b = __int_as_float(u10[u] & 0xffff0000u);
            const float f11a = __int_as_float(u11[u] << 16);
            const float f11b = __int_as_float(u11[u] & 0xffff0000u);
            float s0 = w00[u] * f00a + w01[u] * f01a + w10[u] * f10a + w11[u] * f11a;
            float s1 = w00[u] * f00b + w01[u] * f01b + w10[u] * f10b + w11[u] * f11b;
            ((unsigned*)&S[pp * KPAD + k * 128])[l] = pack2(s0, s1);
        }
    }
    __syncthreads();

    // ---- dconv GEMM: wave = 16 oc, A-frags reused across 2 px-columns ----
    f32x4 dacc0 = {0.f, 0.f, 0.f, 0.f}, dacc1 = {0.f, 0.f, 0.f, 0.f};
    {
        const short* darow = wbs + (wv * 36) * 512 + l * 8;
        const short* srow0 = &S[lr * KPAD + lq * 8];
        const short* srow1 = &S[(16 + lr) * KPAD + lq * 8];
#pragma unroll
        for (int bch = 0; bch < 6; ++bch) {
            bf16x8 af[6], bf0[6], bf1[6];
#pragma unroll
            for (int u = 0; u < 6; ++u) af[u]  = *(const bf16x8*)(darow + (bch * 6 + u) * 512);
#pragma unroll
            for (int u = 0; u < 6; ++u) bf0[u] = *(const bf16x8*)(srow0 + (bch * 6 + u) * 32);
#pragma unroll
            for (int u = 0; u < 6; ++u) bf1[u] = *(const bf16x8*)(srow1 + (bch * 6 + u) * 32);
#pragma unroll
            for (int u = 0; u < 6; ++u) {
                dacc0 = __builtin_amdgcn_mfma_f32_16x16x32_bf16(af[u], bf0[u], dacc0, 0, 0, 0);
                dacc1 = __builtin_amdgcn_mfma_f32_16x16x32_bf16(af[u], bf1[u], dacc1, 0, 0, 0);
            }
        }
    }

    // ---- epilogue: BN + ReLU + residual(f32) ----
    const int ocb = wv * 16 + (lq << 2);
    if (last) {
#pragma unroll
        for (int pf = 0; pf < 2; ++pf) {
            const f32x4 dv = pf ? dacc1 : dacc0;
            const int px = pf * 16 + lr;
#pragma unroll
            for (int r = 0; r < 4; ++r) {
                const int oc = ocb + r;
                const float sc = gv[oc] * rsqrtf(vv[oc] + EPSn);
                float y = (dv[r] - mv[oc]) * sc + bv[oc];
                y = fmaxf(y, 0.f);
                y += xTf[(pix0 + px) * 128 + oc];
                outC[b * CHWn + oc * HWn + sp0 + px] = y;
            }
        }
    } else {
        __syncthreads();                       // all S reads done; alias O on S
        float* O = (float*)S;                  // O[32][132]
#pragma unroll
        for (int pf = 0; pf < 2; ++pf) {
            const f32x4 dv = pf ? dacc1 : dacc0;
            const int px = pf * 16 + lr;
            f32x4 y;
#pragma unroll
            for (int r = 0; r < 4; ++r) {
                const int oc = ocb + r;
                const float sc = gv[oc] * rsqrtf(vv[oc] + EPSn);
                y[r] = fmaxf((dv[r] - mv[oc]) * sc + bv[oc], 0.f);
            }
            *(f32x4*)&O[px * 132 + ocb] = y;
        }
        __syncthreads();
        // coalesced NHWC write + coalesced residual read (f32 + bf16 copies)
#pragma unroll
        for (int it = 0; it < 2; ++it) {
            const int o  = t * 4 + it * 2048;  // 0..4095
            const int qp = o >> 7, qc = o & 127;
            f32x4 yv = *(f32x4*)&O[qp * 132 + qc];
            f32x4 rv = *(const f32x4*)&xTf[(pix0 + qp) * 128 + qc];
            yv += rv;
            *(f32x4*)&outTf[(pix0 + qp) * 128 + qc] = yv;
            uint2 pk;
            pk.x = pack2(yv[0], yv[1]);
            pk.y = pack2(yv[2], yv[3]);
            *(uint2*)&outTb[(pix0 + qp) * 128 + qc] = pk;
        }
    }
}

extern "C" void kernel_launch(void* const* d_in, const int* in_sizes, int n_in,
                              void* d_out, int out_size, void* d_ws, size_t ws_size,
                              hipStream_t stream) {
    (void)in_sizes; (void)n_in; (void)out_size; (void)ws_size;

    const float* hu = (const float*)d_in[0];

    short* wbs  = (short*)d_ws;                          // 3 * 147456 shorts
    short* owbs = wbs + 3 * Cn * KCn;                    // 3 * 36864 shorts
    unsigned short* T0b = (unsigned short*)(owbs + 3 * 32 * KCn);  // Bn*CHWn
    unsigned short* T1b = T0b + Bn * CHWn;
    float* T0f = (float*)(T1b + Bn * CHWn);
    float* T1f = T0f + Bn * CHWn;

    for (int i = 0; i < 3; ++i) {
        cvt_w_shuf<<<(Cn * KCn + 255) / 256, 256, 0, stream>>>(
            (const float*)d_in[3 + 7 * i], wbs + i * Cn * KCn);
        cvt_ow_shuf<<<(32 * KCn + 255) / 256, 256, 0, stream>>>(
            (const float*)d_in[1 + 7 * i], owbs + i * 32 * KCn);
    }

    nchw2nhwc<<<(Bn * HWn) / 64, 256, 0, stream>>>(hu, T0f, T0b);

    const int dils[3] = {2, 4, 8};
    const unsigned short* insb[3] = {T0b, T1b, T0b};
    const float*          insf[3] = {T0f, T1f, T0f};
    float*          outsf[3] = {T1f, T0f, nullptr};
    unsigned short* outsb[3] = {T1b, T0b, nullptr};
    const int nblk = (Bn * HWn) / PXB;            // 576

    for (int i = 0; i < 3; ++i) {
        const float* obv = (const float*)d_in[2 + 7 * i];
        const float* gv  = (const float*)d_in[4 + 7 * i];
        const float* bv  = (const float*)d_in[5 + 7 * i];
        const float* mv  = (const float*)d_in[6 + 7 * i];
        const float* vv  = (const float*)d_in[7 + 7 * i];
        const int last = (i == 2);

        fused_stage<<<nblk, 512, 0, stream>>>(
            insb[i], insf[i], wbs + i * Cn * KCn, owbs + i * 32 * KCn, obv,
            gv, bv, mv, vv, outsf[i], outsb[i],
            last ? (float*)d_out : nullptr, dils[i], last);
    }
}

// Round 16
// 122.643 us; speedup vs baseline: 1.0779x; 1.0779x over previous
//
#include <hip/hip_runtime.h>
#include <math.h>

constexpr int Bn  = 2;
constexpr int Cn  = 128;
constexpr int Hn  = 96;
constexpr int Wn  = 96;
constexpr int HWn = Hn * Wn;        // 9216
constexpr int CHWn = Cn * HWn;      // 1179648
constexpr int KCn = Cn * 9;         // 1152
constexpr float EPSn = 1e-5f;
constexpr int PXB  = 32;            // pixels per block
constexpr int KP5  = 648;           // S row stride (shorts) for 5-tap group

typedef short bf16x8 __attribute__((ext_vector_type(8)));
typedef float f32x4  __attribute__((ext_vector_type(4)));

static __device__ inline short f2bf(float f) {
    union { float f; unsigned u; } v; v.f = f;
    unsigned r = v.u + 0x7fff + ((v.u >> 16) & 1);
    return (short)(r >> 16);
}
static __device__ inline unsigned pack2(float a, float b) {
    unsigned r;
    asm("v_cvt_pk_bf16_f32 %0, %1, %2" : "=v"(r) : "v"(a), "v"(b));
    return r;
}

// Fragment-shuffled dconv weights for all 3 stages in one launch.
// wbs[stage][((wv*36 + j)*64 + l)*8 + e] = w[o=wv*16+(l&15)][c*9+k], kidx=j*32+(l>>4)*8+e
__global__ __launch_bounds__(256) void cvt_w_all(
    const float* __restrict__ w1, const float* __restrict__ w2,
    const float* __restrict__ w3, short* __restrict__ wbs)
{
    const int bid = blockIdx.x;               // 3*576
    const int stage = bid / 576;
    const float* w = (stage == 0) ? w1 : (stage == 1) ? w2 : w3;
    int t = (bid - stage * 576) * 256 + threadIdx.x;
    int e = t & 7, l = (t >> 3) & 63, rest = t >> 9;   // rest 0..287
    int j = rest % 36, wv = rest / 36;
    int lr = l & 15, lq = l >> 4;
    int o = wv * 16 + lr;
    int kidx = j * 32 + lq * 8 + e;
    int k = kidx >> 7, c = kidx & 127;
    wbs[stage * Cn * KCn + t] = f2bf(w[o * KCn + c * 9 + k]);
}

// j-ordered fragment-shuffled offconv weights (M=32 as 2 mh-halves):
// owbs[stage][((mh*36 + j)*64 + l)*8 + e], row o = mh*16+(l&15)
__global__ __launch_bounds__(256) void cvt_ow_all(
    const float* __restrict__ w1, const float* __restrict__ w2,
    const float* __restrict__ w3, short* __restrict__ owbs)
{
    const int bid = blockIdx.x;               // 3*144
    const int stage = bid / 144;
    const float* ow = (stage == 0) ? w1 : (stage == 1) ? w2 : w3;
    int t = (bid - stage * 144) * 256 + threadIdx.x;
    int e = t & 7, l = (t >> 3) & 63, rest = t >> 9;   // rest 0..71
    int j = rest % 36, mh = rest / 36;
    int lr = l & 15, lq = l >> 4;
    int o = mh * 16 + lr;
    int kidx = j * 32 + lq * 8 + e;
    int k = kidx >> 7, c = kidx & 127;
    owbs[stage * 32 * KCn + t] = (o < 27) ? f2bf(ow[o * KCn + c * 9 + k]) : (short)0;
}

// NCHW -> NHWC, dual output: f32 (residual-exact) + bf16 (gather path)
__global__ __launch_bounds__(256) void nchw2nhwc(
    const float* __restrict__ x, float* __restrict__ xTf,
    unsigned short* __restrict__ xTb)
{
    __shared__ float Tl[128][65];
    const int t = threadIdx.x;
    const int pix0 = blockIdx.x * 64;
    const int b   = pix0 / HWn;
    const int sp0 = pix0 - b * HWn;
    const float* xb = x + b * CHWn + sp0 + (t & 63);
    const int c0 = t >> 6;
#pragma unroll 8
    for (int i = 0; i < 32; ++i) {
        const int c = c0 + 4 * i;
        Tl[c][t & 63] = xb[c * HWn];
    }
    __syncthreads();
    float* dstf = xTf + pix0 * 128;
    unsigned short* dstb = xTb + pix0 * 128;
#pragma unroll 8
    for (int i = 0; i < 32; ++i) {
        const int o = t + 256 * i;
        float v = Tl[o & 127][o >> 7];
        dstf[o] = v;
        dstb[o] = (unsigned short)f2bf(v);
    }
}

// One fused residual block: 32 px / 512 threads, K-split im2col (taps 0-4 / 5-8),
// bf16 gathers, f32 residual, fragment-shuffled weights (A reused over 2 px-cols).
__global__ __launch_bounds__(512, 6) void fused_stage(
    const unsigned short* __restrict__ xTb, const float* __restrict__ xTf,
    const short* __restrict__ wbs, const short* __restrict__ owbs,
    const float* __restrict__ obv,
    const float* __restrict__ gv, const float* __restrict__ bv,
    const float* __restrict__ mv, const float* __restrict__ vv,
    float* __restrict__ outTf, unsigned short* __restrict__ outTb,
    float* __restrict__ outC, int dil, int last)
{
    __shared__ short S[PXB * KP5];            // 41472B half-K im2col S[p][k<5][c]
    __shared__ float offL[PXB][18];
    __shared__ float maskL[PXB][9];

    const int t   = threadIdx.x;
    const int l   = t & 63;
    const int wv  = t >> 6;                   // wave 0..7
    const int lh  = l >> 5;                   // pixel half (gather-int)
    const int lc  = l & 31;                   // channel quad (gather-int)
    const int lr  = l & 15, lq = l >> 4;

    // XCD-aware bijective swizzle: 576 blocks = 8 XCDs x 72 contiguous
    const int bid = blockIdx.x;
    const int swz = (bid & 7) * 72 + (bid >> 3);
    const int pix0 = swz * PXB;               // 96%32==0: never crosses a row
    const int b   = pix0 / HWn;
    const int sp0 = pix0 - b * HWn;
    const int hy  = sp0 / Wn;
    const int wx0 = sp0 - hy * Wn;
    const int basep = b * HWn;

    const int mh = wv & 1, jg = wv >> 1;      // offconv wave split
    f32x4 oacc0 = {0.f,0.f,0.f,0.f}, oacc1 = {0.f,0.f,0.f,0.f};

    // ================= K-group 0: taps 0..4 (j 0..19) =================
#pragma unroll
    for (int pi = 0; pi < 2; ++pi) {
        const int pp = wv * 4 + pi * 2 + lh;
#pragma unroll
        for (int k = 0; k < 5; ++k) {
            const int iy = hy + (k / 3 - 1) * dil;
            const int ix = wx0 + pp + (k % 3 - 1) * dil;
            const bool v = (iy >= 0) && (iy < Hn) && (ix >= 0) && (ix < Wn);
            const int aof = v ? (basep + iy * Wn + ix) : basep;
            uint2 val = ((const uint2*)(xTb + aof * 128))[lc];
            val.x = v ? val.x : 0u;  val.y = v ? val.y : 0u;
            ((uint2*)&S[pp * KP5 + k * 128])[lc] = val;
        }
    }
    __syncthreads();
    {   // offconv partial G0: wave (mh,jg), j = jg*5 .. +4, both px-frags
        const short* arow = owbs + (mh * 36 + jg * 5) * 512 + l * 8;
        const short* sr0  = &S[lr * KP5 + jg * 5 * 32 + lq * 8];
        const short* sr1  = &S[(16 + lr) * KP5 + jg * 5 * 32 + lq * 8];
#pragma unroll
        for (int jj = 0; jj < 5; ++jj) {
            bf16x8 af  = *(const bf16x8*)(arow + jj * 512);
            bf16x8 bf0 = *(const bf16x8*)(sr0 + jj * 32);
            bf16x8 bf1 = *(const bf16x8*)(sr1 + jj * 32);
            oacc0 = __builtin_amdgcn_mfma_f32_16x16x32_bf16(af, bf0, oacc0, 0, 0, 0);
            oacc1 = __builtin_amdgcn_mfma_f32_16x16x32_bf16(af, bf1, oacc1, 0, 0, 0);
        }
    }
    __syncthreads();

    // ================= K-group 1: taps 5..8 (j 20..35) =================
#pragma unroll
    for (int pi = 0; pi < 2; ++pi) {
        const int pp = wv * 4 + pi * 2 + lh;
#pragma unroll
        for (int k = 5; k < 9; ++k) {
            const int iy = hy + (k / 3 - 1) * dil;
            const int ix = wx0 + pp + (k % 3 - 1) * dil;
            const bool v = (iy >= 0) && (iy < Hn) && (ix >= 0) && (ix < Wn);
            const int aof = v ? (basep + iy * Wn + ix) : basep;
            uint2 val = ((const uint2*)(xTb + aof * 128))[lc];
            val.x = v ? val.x : 0u;  val.y = v ? val.y : 0u;
            ((uint2*)&S[pp * KP5 + (k - 5) * 128])[lc] = val;
        }
    }
    __syncthreads();
    {   // offconv partial G1: j = 20 + jg*4 .. +3
        const short* arow = owbs + (mh * 36 + 20 + jg * 4) * 512 + l * 8;
        const short* sr0  = &S[lr * KP5 + jg * 4 * 32 + lq * 8];
        const short* sr1  = &S[(16 + lr) * KP5 + jg * 4 * 32 + lq * 8];
#pragma unroll
        for (int jj = 0; jj < 4; ++jj) {
            bf16x8 af  = *(const bf16x8*)(arow + jj * 512);
            bf16x8 bf0 = *(const bf16x8*)(sr0 + jj * 32);
            bf16x8 bf1 = *(const bf16x8*)(sr1 + jj * 32);
            oacc0 = __builtin_amdgcn_mfma_f32_16x16x32_bf16(af, bf0, oacc0, 0, 0, 0);
            oacc1 = __builtin_amdgcn_mfma_f32_16x16x32_bf16(af, bf1, oacc1, 0, 0, 0);
        }
    }
    __syncthreads();                           // S int reads done

    // ---- offconv reduce over jg (4-way) ----
    float* red = (float*)S;                    // 16KB alias
    *(f32x4*)&red[(wv * 2 + 0) * 256 + l * 4] = oacc0;
    *(f32x4*)&red[(wv * 2 + 1) * 256 + l * 4] = oacc1;
    __syncthreads();
    if (wv < 4) {                              // wave w -> (mh=w&1, pxf=w>>1)
        const int m2 = wv & 1, pxf = wv >> 1;
        f32x4 sm = {0.f,0.f,0.f,0.f};
#pragma unroll
        for (int g = 0; g < 4; ++g)
            sm += *(const f32x4*)&red[((g * 2 + m2) * 2 + pxf) * 256 + l * 4];
        const int px = pxf * 16 + lr;
#pragma unroll
        for (int r = 0; r < 4; ++r) {
            int oc = m2 * 16 + lq * 4 + r;
            if (oc < 18) {
                offL[px][oc] = sm[r] + obv[oc];
            } else if (oc < 27) {
                float z = sm[r] + obv[oc];
                maskL[px][oc - 18] = 1.f / (1.f + expf(-z));
            }
        }
    }
    __syncthreads();

    // ---- bilinear params: lane j(<36) -> (pp=wv*4+j/9, k=j%9) ----
    int pw0i = 0, pw1i = 0, pw2i = 0, pw3i = 0, pa0 = 0, pa1 = 0, pdx = 0;
    if (l < 36) {
        const int p = wv * 4 + l / 9;
        const int k = l - 9 * (l / 9);
        const float offy = offL[p][2 * k];
        const float offx = offL[p][2 * k + 1];
        const float m    = maskL[p][k];
        const float py = (float)(hy + (k / 3 - 1) * dil) + offy;
        const float px = (float)(wx0 + p + (k % 3 - 1) * dil) + offx;
        const float y0f = floorf(py), x0f = floorf(px);
        const float ly = py - y0f, lx = px - x0f;
        const int y0 = (int)y0f, x0 = (int)x0f;
        const float yv0 = (y0 >= 0 && y0 < Hn)      ? 1.f : 0.f;
        const float yv1 = (y0 >= -1 && y0 < Hn - 1) ? 1.f : 0.f;
        const float xv0 = (x0 >= 0 && x0 < Wn)      ? 1.f : 0.f;
        const float xv1 = (x0 >= -1 && x0 < Wn - 1) ? 1.f : 0.f;
        const float wy0 = (1.f - ly) * yv0 * m;
        const float wy1 = ly * yv1 * m;
        const float wxa = (1.f - lx) * xv0;
        const float wxb = lx * xv1;
        pw0i = __float_as_int(wy0 * wxa);
        pw1i = __float_as_int(wy0 * wxb);
        pw2i = __float_as_int(wy1 * wxa);
        pw3i = __float_as_int(wy1 * wxb);
        const int y0c = min(max(y0, 0), Hn - 1), y1c = min(max(y0 + 1, 0), Hn - 1);
        const int x0c = min(max(x0, 0), Wn - 1), x1c = min(max(x0 + 1, 0), Wn - 1);
        pa0 = (basep + y0c * Wn + x0c) * 128;
        pa1 = (basep + y1c * Wn + x1c) * 128;
        pdx = (x1c - x0c) * 128;
    }
    // no barrier: params wave-internal; S reads (red) already sync'd

    f32x4 dacc0 = {0.f,0.f,0.f,0.f}, dacc1 = {0.f,0.f,0.f,0.f};

    // ================= dconv K-group 0: taps 0..4 =================
#pragma unroll
    for (int di = 0; di < 4; ++di) {
        const int pp = wv * 4 + di;
#pragma unroll
        for (int k = 0; k < 5; ++k) {
            const int i = di * 9 + k;
            const float w00 = __int_as_float(__builtin_amdgcn_readlane(pw0i, i));
            const float w01 = __int_as_float(__builtin_amdgcn_readlane(pw1i, i));
            const float w10 = __int_as_float(__builtin_amdgcn_readlane(pw2i, i));
            const float w11 = __int_as_float(__builtin_amdgcn_readlane(pw3i, i));
            const int a00 = __builtin_amdgcn_readlane(pa0, i);
            const int a11 = __builtin_amdgcn_readlane(pa1, i);
            const int dxk = __builtin_amdgcn_readlane(pdx, i);
            const unsigned short* xp = xTb + a00;
            const unsigned short* xq = xTb + a11;
            unsigned u00 = ((const unsigned*)xp)[l];
            unsigned u01 = ((const unsigned*)(xp + dxk))[l];
            unsigned u10 = ((const unsigned*)(xq - dxk))[l];
            unsigned u11 = ((const unsigned*)xq)[l];
            float s0 = w00 * __int_as_float(u00 << 16) + w01 * __int_as_float(u01 << 16)
                     + w10 * __int_as_float(u10 << 16) + w11 * __int_as_float(u11 << 16);
            float s1 = w00 * __int_as_float(u00 & 0xffff0000u) + w01 * __int_as_float(u01 & 0xffff0000u)
                     + w10 * __int_as_float(u10 & 0xffff0000u) + w11 * __int_as_float(u11 & 0xffff0000u);
            ((unsigned*)&S[pp * KP5 + k * 128])[l] = pack2(s0, s1);
        }
    }
    __syncthreads();
    {   // dconv partial G0: j 0..19, wave = 16 oc, 2 px-cols
        const short* darow = wbs + (wv * 36) * 512 + l * 8;
        const short* sr0   = &S[lr * KP5 + lq * 8];
        const short* sr1   = &S[(16 + lr) * KP5 + lq * 8];
#pragma unroll
        for (int j = 0; j < 20; ++j) {
            bf16x8 af  = *(const bf16x8*)(darow + j * 512);
            bf16x8 bf0 = *(const bf16x8*)(sr0 + j * 32);
            bf16x8 bf1 = *(const bf16x8*)(sr1 + j * 32);
            dacc0 = __builtin_amdgcn_mfma_f32_16x16x32_bf16(af, bf0, dacc0, 0, 0, 0);
            dacc1 = __builtin_amdgcn_mfma_f32_16x16x32_bf16(af, bf1, dacc1, 0, 0, 0);
        }
    }
    __syncthreads();

    // ================= dconv K-group 1: taps 5..8 =================
#pragma unroll
    for (int di = 0; di < 4; ++di) {
        const int pp = wv * 4 + di;
#pragma unroll
        for (int k = 5; k < 9; ++k) {
            const int i = di * 9 + k;
            const float w00 = __int_as_float(__builtin_amdgcn_readlane(pw0i, i));
            const float w01 = __int_as_float(__builtin_amdgcn_readlane(pw1i, i));
            const float w10 = __int_as_float(__builtin_amdgcn_readlane(pw2i, i));
            const float w11 = __int_as_float(__builtin_amdgcn_readlane(pw3i, i));
            const int a00 = __builtin_amdgcn_readlane(pa0, i);
            const int a11 = __builtin_amdgcn_readlane(pa1, i);
            const int dxk = __builtin_amdgcn_readlane(pdx, i);
            const unsigned short* xp = xTb + a00;
            const unsigned short* xq = xTb + a11;
            unsigned u00 = ((const unsigned*)xp)[l];
            unsigned u01 = ((const unsigned*)(xp + dxk))[l];
            unsigned u10 = ((const unsigned*)(xq - dxk))[l];
            unsigned u11 = ((const unsigned*)xq)[l];
            float s0 = w00 * __int_as_float(u00 << 16) + w01 * __int_as_float(u01 << 16)
                     + w10 * __int_as_float(u10 << 16) + w11 * __int_as_float(u11 << 16);
            float s1 = w00 * __int_as_float(u00 & 0xffff0000u) + w01 * __int_as_float(u01 & 0xffff0000u)
                     + w10 * __int_as_float(u10 & 0xffff0000u) + w11 * __int_as_float(u11 & 0xffff0000u);
            ((unsigned*)&S[pp * KP5 + (k - 5) * 128])[l] = pack2(s0, s1);
        }
    }
    __syncthreads();
    {   // dconv partial G1: j 20..35
        const short* darow = wbs + (wv * 36 + 20) * 512 + l * 8;
        const short* sr0   = &S[lr * KP5 + lq * 8];
        const short* sr1   = &S[(16 + lr) * KP5 + lq * 8];
#pragma unroll
        for (int j = 0; j < 16; ++j) {
            bf16x8 af  = *(const bf16x8*)(darow + j * 512);
            bf16x8 bf0 = *(const bf16x8*)(sr0 + j * 32);
            bf16x8 bf1 = *(const bf16x8*)(sr1 + j * 32);
            dacc0 = __builtin_amdgcn_mfma_f32_16x16x32_bf16(af, bf0, dacc0, 0, 0, 0);
            dacc1 = __builtin_amdgcn_mfma_f32_16x16x32_bf16(af, bf1, dacc1, 0, 0, 0);
        }
    }

    // ---- epilogue: BN + ReLU + residual(f32) ----
    const int ocb = wv * 16 + (lq << 2);
    if (last) {
#pragma unroll
        for (int pf = 0; pf < 2; ++pf) {
            const f32x4 dv = pf ? dacc1 : dacc0;
            const int px = pf * 16 + lr;
#pragma unroll
            for (int r = 0; r < 4; ++r) {
                const int oc = ocb + r;
                const float sc = gv[oc] * rsqrtf(vv[oc] + EPSn);
                float y = (dv[r] - mv[oc]) * sc + bv[oc];
                y = fmaxf(y, 0.f);
                y += xTf[(pix0 + px) * 128 + oc];
                outC[b * CHWn + oc * HWn + sp0 + px] = y;
            }
        }
    } else {
        __syncthreads();                       // all S reads done; alias O on S
        float* O = (float*)S;                  // O[32][132] = 16.9KB
#pragma unroll
        for (int pf = 0; pf < 2; ++pf) {
            const f32x4 dv = pf ? dacc1 : dacc0;
            const int px = pf * 16 + lr;
            f32x4 y;
#pragma unroll
            for (int r = 0; r < 4; ++r) {
                const int oc = ocb + r;
                const float sc = gv[oc] * rsqrtf(vv[oc] + EPSn);
                y[r] = fmaxf((dv[r] - mv[oc]) * sc + bv[oc], 0.f);
            }
            *(f32x4*)&O[px * 132 + ocb] = y;
        }
        __syncthreads();
#pragma unroll
        for (int it = 0; it < 2; ++it) {
            const int o  = t * 4 + it * 2048;  // 0..4095
            const int qp = o >> 7, qc = o & 127;
            f32x4 yv = *(f32x4*)&O[qp * 132 + qc];
            f32x4 rv = *(const f32x4*)&xTf[(pix0 + qp) * 128 + qc];
            yv += rv;
            *(f32x4*)&outTf[(pix0 + qp) * 128 + qc] = yv;
            uint2 pk;
            pk.x = pack2(yv[0], yv[1]);
            pk.y = pack2(yv[2], yv[3]);
            *(uint2*)&outTb[(pix0 + qp) * 128 + qc] = pk;
        }
    }
}

extern "C" void kernel_launch(void* const* d_in, const int* in_sizes, int n_in,
                              void* d_out, int out_size, void* d_ws, size_t ws_size,
                              hipStream_t stream) {
    (void)in_sizes; (void)n_in; (void)out_size; (void)ws_size;

    const float* hu = (const float*)d_in[0];

    short* wbs  = (short*)d_ws;                          // 3 * 147456 shorts
    short* owbs = wbs + 3 * Cn * KCn;                    // 3 * 36864 shorts
    unsigned short* T0b = (unsigned short*)(owbs + 3 * 32 * KCn);  // Bn*CHWn
    unsigned short* T1b = T0b + Bn * CHWn;
    float* T0f = (float*)(T1b + Bn * CHWn);
    float* T1f = T0f + Bn * CHWn;

    cvt_w_all<<<3 * 576, 256, 0, stream>>>(
        (const float*)d_in[3], (const float*)d_in[10], (const float*)d_in[17], wbs);
    cvt_ow_all<<<3 * 144, 256, 0, stream>>>(
        (const float*)d_in[1], (const float*)d_in[8], (const float*)d_in[15], owbs);

    nchw2nhwc<<<(Bn * HWn) / 64, 256, 0, stream>>>(hu, T0f, T0b);

    const int dils[3] = {2, 4, 8};
    const unsigned short* insb[3] = {T0b, T1b, T0b};
    const float*          insf[3] = {T0f, T1f, T0f};
    float*          outsf[3] = {T1f, T0f, nullptr};
    unsigned short* outsb[3] = {T1b, T0b, nullptr};
    const int nblk = (Bn * HWn) / PXB;            // 576

    for (int i = 0; i < 3; ++i) {
        const float* obv = (const float*)d_in[2 + 7 * i];
        const float* gv  = (const float*)d_in[4 + 7 * i];
        const float* bv  = (const float*)d_in[5 + 7 * i];
        const float* mv  = (const float*)d_in[6 + 7 * i];
        const float* vv  = (const float*)d_in[7 + 7 * i];
        const int last = (i == 2);

        fused_stage<<<nblk, 512, 0, stream>>>(
            insb[i], insf[i], wbs + i * Cn * KCn, owbs + i * 32 * KCn, obv,
            gv, bv, mv, vv, outsf[i], outsb[i],
            last ? (float*)d_out : nullptr, dils[i], last);
    }
}